// Round 3
// baseline (708.455 us; speedup 1.0000x reference)
//
#include <hip/hip_runtime.h>
#include <hip/hip_fp16.h>
#include <stdint.h>

#define B_ROWS 4096
#define N_PAT  8192
#define N_NEU  1024

typedef _Float16 f16x8 __attribute__((ext_vector_type(8)));
typedef _Float16 f16x4 __attribute__((ext_vector_type(4)));
typedef float    f32x4 __attribute__((ext_vector_type(4)));

// ---------------- fp32 -> fp16 elementwise convert (vectorized) ----------------
__global__ __launch_bounds__(256) void convert_f32_f16(
    const float* __restrict__ in, _Float16* __restrict__ out, int n4) {
  int idx    = blockIdx.x * 256 + threadIdx.x;
  int stride = gridDim.x * 256;
  for (int i = idx; i < n4; i += stride) {
    float4 v = reinterpret_cast<const float4*>(in)[i];
    f16x4 h  = { (_Float16)v.x, (_Float16)v.y, (_Float16)v.z, (_Float16)v.w };
    reinterpret_cast<f16x4*>(out)[i] = h;
  }
}

// ---------------- fp32 [rows][cols] -> fp16 transpose [cols][rows] ----------------
__global__ __launch_bounds__(256) void transpose_f32_f16(
    const float* __restrict__ in, _Float16* __restrict__ out, int rows, int cols) {
  __shared__ float tile[32][33];
  int c0 = blockIdx.x * 32, r0 = blockIdx.y * 32;
  int tx = threadIdx.x, ty = threadIdx.y;  // 32 x 8
  #pragma unroll
  for (int i = 0; i < 32; i += 8)
    tile[ty + i][tx] = in[(size_t)(r0 + ty + i) * cols + c0 + tx];
  __syncthreads();
  #pragma unroll
  for (int i = 0; i < 32; i += 8)
    out[(size_t)(c0 + ty + i) * rows + r0 + tx] = (_Float16)tile[tx][ty + i];
}

// ---------------- async global->LDS, 16B per lane, wave-uniform LDS base ----------------
__device__ __forceinline__ void gload_lds16(const _Float16* g, _Float16* l) {
  __builtin_amdgcn_global_load_lds(
      (const __attribute__((address_space(1))) uint32_t*)g,
      (__attribute__((address_space(3))) uint32_t*)l, 16, 0, 0);
}

// ---------------- GEMM1: C[M,N] = A[M,K] @ Bt[N,K]^T, BK=64, swizzled LDS ----------------
// 128x128 tile, BK=64 (32 MFMA per barrier pair), 4 waves 2x2, 64x64 per wave.
// LDS tiles [128][64] f16 (128B rows). XOR swizzle: granule (16B) g at row r is
// stored at g^(r&7). Staging pre-swizzles the GLOBAL source (linear LDS dest,
// rule #21); ds_read applies the same XOR. Uniform 8 lanes/granule = b128 optimum.
// XCD swizzle: 8-n-column slab per XCD (B slab 2MB L2-resident).
__global__ __launch_bounds__(256) void gemm1_bt64(
    const _Float16* __restrict__ A, const _Float16* __restrict__ Bt,
    _Float16* __restrict__ C, int M, int N, int K) {
  __shared__ _Float16 As[128 * 64];
  __shared__ _Float16 Bs[128 * 64];
  const int t    = threadIdx.x;
  const int lane = t & 63;
  const int w    = t >> 6;
  const int wr   = w >> 1;
  const int wc   = w & 1;

  // T1: bijective XCD remap (nwg = gx*gy, gx=M/128=32, divisible by 8)
  const int gx  = gridDim.x;                 // m tiles (32)
  const int nwg = gx * gridDim.y;
  const int lin = blockIdx.y * gx + blockIdx.x;
  const int swz = (lin & 7) * (nwg >> 3) + (lin >> 3);
  const int m0  = (swz % gx) * 128;
  const int n0  = (swz / gx) * 128;

  // staging geometry: per wave-issue 8 rows x 128B. Row r = j*32 + w*8 + (lane>>3).
  // source granule = (lane&7) ^ ((lane>>3)&7)  (inverse swizzle, r&7 == (lane>>3)&7)
  const int srow = w * 8 + (lane >> 3);
  const int gsrc = ((lane & 7) ^ ((lane >> 3) & 7)) * 8;  // element offset
  const _Float16* gA = A  + (size_t)(m0 + srow) * K + gsrc;
  const _Float16* gB = Bt + (size_t)(n0 + srow) * K + gsrc;
  const size_t rowjump = (size_t)32 * K;  // issue j is 32 rows below
  _Float16* lA = As + (size_t)(w * 8) * 64;
  _Float16* lB = Bs + (size_t)(w * 8) * 64;

  const int lrow = lane & 15;  // fragment row (A) / col (B)
  const int kg   = lane >> 4;  // k-group 0..3
  const int sw   = lrow & 7;   // read-side XOR term

  f32x4 acc[4][4] = {};

  for (int kt = 0; kt < K; kt += 64) {
    #pragma unroll
    for (int j = 0; j < 4; ++j) gload_lds16(gA + j * rowjump + kt, lA + j * 32 * 64);
    #pragma unroll
    for (int j = 0; j < 4; ++j) gload_lds16(gB + j * rowjump + kt, lB + j * 32 * 64);
    __syncthreads();

    f16x8 af[4][2], bf[4][2];
    #pragma unroll
    for (int mi = 0; mi < 4; ++mi) {
      #pragma unroll
      for (int ks = 0; ks < 2; ++ks)
        af[mi][ks] = *reinterpret_cast<const f16x8*>(
            &As[(wr * 64 + mi * 16 + lrow) * 64 + (((ks * 4 + kg) ^ sw) * 8)]);
    }
    #pragma unroll
    for (int ni = 0; ni < 4; ++ni) {
      #pragma unroll
      for (int ks = 0; ks < 2; ++ks)
        bf[ni][ks] = *reinterpret_cast<const f16x8*>(
            &Bs[(wc * 64 + ni * 16 + lrow) * 64 + (((ks * 4 + kg) ^ sw) * 8)]);
    }
    #pragma unroll
    for (int mi = 0; mi < 4; ++mi) {
      #pragma unroll
      for (int ni = 0; ni < 4; ++ni) {
        acc[mi][ni] = __builtin_amdgcn_mfma_f32_16x16x32_f16(af[mi][0], bf[ni][0], acc[mi][ni], 0, 0, 0);
        acc[mi][ni] = __builtin_amdgcn_mfma_f32_16x16x32_f16(af[mi][1], bf[ni][1], acc[mi][ni], 0, 0, 0);
      }
    }
    __syncthreads();
  }

  const int crow = (lane >> 4) * 4;
  const int ccol = lane & 15;
  #pragma unroll
  for (int mi = 0; mi < 4; ++mi) {
    #pragma unroll
    for (int ni = 0; ni < 4; ++ni) {
      #pragma unroll
      for (int r = 0; r < 4; ++r) {
        int row = m0 + wr * 64 + mi * 16 + crow + r;
        int col = n0 + wc * 64 + ni * 16 + ccol;
        C[(size_t)row * N + col] = (_Float16)acc[mi][ni][r];
      }
    }
  }
}

// ---------------- split-K GEMM2: Cp[z][M][N] = A[M,k0:k1] @ Bt[N,k0:k1]^T ----------------
// Double-buffered LDS, issue-early staging. fp32 partial per K-split (blockIdx.z).
__global__ __launch_bounds__(256, 4) void gemm_bt_splitk(
    const _Float16* __restrict__ A, const _Float16* __restrict__ Bt,
    float* __restrict__ Cp, int M, int N, int K, int KS) {
  __shared__ _Float16 As[2][128 * 32];
  __shared__ _Float16 Bs[2][128 * 32];
  const int t    = threadIdx.x;
  const int lane = t & 63;
  const int w    = t >> 6;
  const int wr   = w >> 1;
  const int wc   = w & 1;

  // T1: remap (x,y) within each z slice (gx*gy = 256, divisible by 8)
  const int gx   = gridDim.x;
  const int nwg  = gx * gridDim.y;
  const int lin  = blockIdx.y * gx + blockIdx.x;
  const int swz  = (lin & 7) * (nwg >> 3) + (lin >> 3);
  const int m0   = (swz % gx) * 128;
  const int n0   = (swz / gx) * 128;
  const int k0   = blockIdx.z * KS;

  const int srow = w * 16 + (lane >> 2);
  const int scol = (lane & 3) * 8;
  const _Float16* gA = A  + (size_t)(m0 + srow) * K + scol + k0;
  const _Float16* gB = Bt + (size_t)(n0 + srow) * K + scol + k0;
  const size_t jump = (size_t)64 * K;

  const int lrow = lane & 15;
  const int kg   = lane >> 4;
  const int nt   = KS / 32;

  f32x4 acc[4][4] = {};

  {
    _Float16* lA = &As[0][w * 512];
    _Float16* lB = &Bs[0][w * 512];
    gload_lds16(gA, lA);
    gload_lds16(gA + jump, lA + 2048);
    gload_lds16(gB, lB);
    gload_lds16(gB + jump, lB + 2048);
  }
  __syncthreads();

  for (int it = 0; it < nt; ++it) {
    const int cur = it & 1;
    if (it + 1 < nt) {
      const int kt = (it + 1) * 32;
      _Float16* lA = &As[cur ^ 1][w * 512];
      _Float16* lB = &Bs[cur ^ 1][w * 512];
      gload_lds16(gA + kt, lA);
      gload_lds16(gA + jump + kt, lA + 2048);
      gload_lds16(gB + kt, lB);
      gload_lds16(gB + jump + kt, lB + 2048);
    }

    f16x8 af[4], bf[4];
    #pragma unroll
    for (int mi = 0; mi < 4; ++mi)
      af[mi] = *reinterpret_cast<const f16x8*>(&As[cur][(wr * 64 + mi * 16 + lrow) * 32 + kg * 8]);
    #pragma unroll
    for (int ni = 0; ni < 4; ++ni)
      bf[ni] = *reinterpret_cast<const f16x8*>(&Bs[cur][(wc * 64 + ni * 16 + lrow) * 32 + kg * 8]);
    #pragma unroll
    for (int mi = 0; mi < 4; ++mi) {
      #pragma unroll
      for (int ni = 0; ni < 4; ++ni)
        acc[mi][ni] = __builtin_amdgcn_mfma_f32_16x16x32_f16(af[mi], bf[ni], acc[mi][ni], 0, 0, 0);
    }
    __syncthreads();
  }

  float* Cz = Cp + (size_t)blockIdx.z * M * N;
  const int crow = (lane >> 4) * 4;
  const int ccol = lane & 15;
  #pragma unroll
  for (int mi = 0; mi < 4; ++mi) {
    #pragma unroll
    for (int ni = 0; ni < 4; ++ni) {
      #pragma unroll
      for (int r = 0; r < 4; ++r) {
        int row = m0 + wr * 64 + mi * 16 + crow + r;
        int col = n0 + wc * 64 + ni * 16 + ccol;
        Cz[(size_t)row * N + col] = acc[mi][ni][r];
      }
    }
  }
}

// ---------------- sum SPLIT fp32 partials -> OUT_T ----------------
template <typename OUT_T, int SPLIT>
__global__ __launch_bounds__(256) void reduce_partials(
    const float* __restrict__ Cp, OUT_T* __restrict__ out, int n4, int stride4) {
  int idx    = blockIdx.x * 256 + threadIdx.x;
  int stride = gridDim.x * 256;
  for (int i = idx; i < n4; i += stride) {
    float4 a = reinterpret_cast<const float4*>(Cp)[i];
    #pragma unroll
    for (int s = 1; s < SPLIT; ++s) {
      float4 b = reinterpret_cast<const float4*>(Cp)[(size_t)s * stride4 + i];
      a.x += b.x; a.y += b.y; a.z += b.z; a.w += b.w;
    }
    if constexpr (sizeof(OUT_T) == 2) {
      f16x4 h = { (_Float16)a.x, (_Float16)a.y, (_Float16)a.z, (_Float16)a.w };
      reinterpret_cast<f16x4*>(out)[i] = h;
    } else {
      reinterpret_cast<float4*>(out)[i] = a;
    }
  }
}

// ---------------- in-place row softmax over N=8192 fp16 scores ----------------
__global__ __launch_bounds__(256) void softmax_rows(_Float16* __restrict__ S, int N) {
  const int t = threadIdx.x;
  f16x8* pv = reinterpret_cast<f16x8*>(S + (size_t)blockIdx.x * N);
  float v[32];
  float m = -3.0e38f;
  #pragma unroll
  for (int i = 0; i < 4; ++i) {
    f16x8 h = pv[i * 256 + t];
    #pragma unroll
    for (int e = 0; e < 8; ++e) {
      float f = (float)h[e];
      v[i * 8 + e] = f;
      m = fmaxf(m, f);
    }
  }
  #pragma unroll
  for (int o = 32; o; o >>= 1) m = fmaxf(m, __shfl_xor(m, o));
  __shared__ float redm[4];
  if ((t & 63) == 0) redm[t >> 6] = m;
  __syncthreads();
  m = fmaxf(fmaxf(redm[0], redm[1]), fmaxf(redm[2], redm[3]));

  float s = 0.f;
  #pragma unroll
  for (int i = 0; i < 32; ++i) { v[i] = __expf(v[i] - m); s += v[i]; }
  #pragma unroll
  for (int o = 32; o; o >>= 1) s += __shfl_xor(s, o);
  __shared__ float reds[4];
  if ((t & 63) == 0) reds[t >> 6] = s;
  __syncthreads();
  s = reds[0] + reds[1] + reds[2] + reds[3];
  const float inv = 1.0f / s;

  #pragma unroll
  for (int i = 0; i < 4; ++i) {
    f16x8 h;
    #pragma unroll
    for (int e = 0; e < 8; ++e) h[e] = (_Float16)(v[i * 8 + e] * inv);
    pv[i * 256 + t] = h;
  }
}

extern "C" void kernel_launch(void* const* d_in, const int* in_sizes, int n_in,
                              void* d_out, int out_size, void* d_ws, size_t ws_size,
                              hipStream_t stream) {
  const float* x        = (const float*)d_in[0];
  const float* patterns = (const float*)d_in[1];
  float* out            = (float*)d_out;
  char* ws = (char*)d_ws;

  _Float16* Xb   = (_Float16*)(ws);                          //   8 MB [4096][1024]
  _Float16* Pb   = (_Float16*)(ws + ((size_t)8  << 20));     //  16 MB [8192][1024]
  _Float16* PbT  = (_Float16*)(ws + ((size_t)24 << 20));     //  16 MB [1024][8192]
  _Float16* S    = (_Float16*)(ws + ((size_t)40 << 20));     //  64 MB [4096][8192]
  float*    part = (float*)   (ws + ((size_t)104 << 20));    //  split x 16 MB fp32 partials

  const size_t base = (size_t)104 << 20;
  const int split = (ws_size >= base + ((size_t)64 << 20)) ? 4
                  : (ws_size >= base + ((size_t)32 << 20)) ? 2 : 1;

  convert_f32_f16<<<dim3(1024), dim3(256), 0, stream>>>(x, Xb, (B_ROWS * N_NEU) / 4);
  convert_f32_f16<<<dim3(2048), dim3(256), 0, stream>>>(patterns, Pb, (N_PAT * N_NEU) / 4);
  transpose_f32_f16<<<dim3(N_NEU / 32, N_PAT / 32), dim3(32, 8), 0, stream>>>(patterns, PbT, N_PAT, N_NEU);

  const int n4 = (B_ROWS * N_NEU) / 4;
  const int stride4 = n4;

  for (int it = 0; it < 3; ++it) {
    // scores = Xb @ Pb^T  (TEMPERATURE == 1.0)
    gemm1_bt64<<<dim3(B_ROWS / 128, N_PAT / 128), dim3(256), 0, stream>>>(
        Xb, Pb, S, B_ROWS, N_PAT, N_NEU);
    softmax_rows<<<dim3(B_ROWS), dim3(256), 0, stream>>>(S, N_PAT);

    // new_x = probs @ P == probs @ (PbT)^T   (M=4096, N=1024, K=8192)
    if (split > 1) {
      gemm_bt_splitk<<<dim3(B_ROWS / 128, N_NEU / 128, split), dim3(256), 0, stream>>>(
          S, PbT, part, B_ROWS, N_NEU, N_PAT, N_PAT / split);
      if (it < 2) {
        if (split == 4)
          reduce_partials<_Float16, 4><<<dim3(2048), dim3(256), 0, stream>>>(part, Xb, n4, stride4);
        else
          reduce_partials<_Float16, 2><<<dim3(2048), dim3(256), 0, stream>>>(part, Xb, n4, stride4);
      } else {
        if (split == 4)
          reduce_partials<float, 4><<<dim3(2048), dim3(256), 0, stream>>>(part, out, n4, stride4);
        else
          reduce_partials<float, 2><<<dim3(2048), dim3(256), 0, stream>>>(part, out, n4, stride4);
      }
    } else {
      gemm_bt_splitk<<<dim3(B_ROWS / 128, N_NEU / 128, 1), dim3(256), 0, stream>>>(
          S, PbT, part, B_ROWS, N_NEU, N_PAT, N_PAT);
      if (it < 2)
        reduce_partials<_Float16, 1><<<dim3(2048), dim3(256), 0, stream>>>(part, Xb, n4, stride4);
      else
        reduce_partials<float, 1><<<dim3(2048), dim3(256), 0, stream>>>(part, out, n4, stride4);
    }
  }
}

// Round 4
// 617.659 us; speedup vs baseline: 1.1470x; 1.1470x over previous
//
#include <hip/hip_runtime.h>
#include <hip/hip_fp16.h>
#include <stdint.h>

#define B_ROWS 4096
#define N_PAT  8192
#define N_NEU  1024

typedef _Float16 f16x8 __attribute__((ext_vector_type(8)));
typedef _Float16 f16x4 __attribute__((ext_vector_type(4)));
typedef float    f32x4 __attribute__((ext_vector_type(4)));

// ---------------- fp32 -> fp16 elementwise convert (vectorized) ----------------
__global__ __launch_bounds__(256) void convert_f32_f16(
    const float* __restrict__ in, _Float16* __restrict__ out, int n4) {
  int idx    = blockIdx.x * 256 + threadIdx.x;
  int stride = gridDim.x * 256;
  for (int i = idx; i < n4; i += stride) {
    float4 v = reinterpret_cast<const float4*>(in)[i];
    f16x4 h  = { (_Float16)v.x, (_Float16)v.y, (_Float16)v.z, (_Float16)v.w };
    reinterpret_cast<f16x4*>(out)[i] = h;
  }
}

// ---------------- fp32 [rows][cols] -> fp16 transpose [cols][rows] ----------------
__global__ __launch_bounds__(256) void transpose_f32_f16(
    const float* __restrict__ in, _Float16* __restrict__ out, int rows, int cols) {
  __shared__ float tile[32][33];
  int c0 = blockIdx.x * 32, r0 = blockIdx.y * 32;
  int tx = threadIdx.x, ty = threadIdx.y;  // 32 x 8
  #pragma unroll
  for (int i = 0; i < 32; i += 8)
    tile[ty + i][tx] = in[(size_t)(r0 + ty + i) * cols + c0 + tx];
  __syncthreads();
  #pragma unroll
  for (int i = 0; i < 32; i += 8)
    out[(size_t)(c0 + ty + i) * rows + r0 + tx] = (_Float16)tile[tx][ty + i];
}

// ---------------- async global->LDS, 16B per lane, wave-uniform LDS base ----------------
__device__ __forceinline__ void gload_lds16(const _Float16* g, _Float16* l) {
  __builtin_amdgcn_global_load_lds(
      (const __attribute__((address_space(1))) uint32_t*)g,
      (__attribute__((address_space(3))) uint32_t*)l, 16, 0, 0);
}

// ---------------- C[z][M,N] = A[M,k0:k1] @ Bt[N,k0:k1]^T, dbuf + issue-early ----------------
// The round-2-proven structure (1057 TF): 128x128 tile, BK=32, double-buffered
// LDS, STAGE(t+1) issued BEFORE ds_read+MFMA of tile t, single barrier per step.
// Natural (x-fastest) block order — NO XCD remap (it thrashed L2, round 3).
// Used for GEMM1 (OUT=f16, gridDim.z=1, KS=K) and GEMM2 (OUT=f32 partials, z=split).
template <typename OUT_T>
__global__ __launch_bounds__(256, 4) void gemm_bt_db(
    const _Float16* __restrict__ A, const _Float16* __restrict__ Bt,
    OUT_T* __restrict__ C, int M, int N, int K, int KS) {
  __shared__ _Float16 As[2][128 * 32];
  __shared__ _Float16 Bs[2][128 * 32];
  const int t    = threadIdx.x;
  const int lane = t & 63;
  const int w    = t >> 6;
  const int wr   = w >> 1;
  const int wc   = w & 1;
  const int m0   = blockIdx.x * 128;
  const int n0   = blockIdx.y * 128;
  const int k0   = blockIdx.z * KS;

  const int srow = w * 16 + (lane >> 2);
  const int scol = (lane & 3) * 8;
  const _Float16* gA = A  + (size_t)(m0 + srow) * K + scol + k0;
  const _Float16* gB = Bt + (size_t)(n0 + srow) * K + scol + k0;
  const size_t jump = (size_t)64 * K;

  const int lrow = lane & 15;
  const int kg   = lane >> 4;
  const int nt   = KS / 32;

  f32x4 acc[4][4] = {};

  // prologue: stage tile 0 into buffer 0
  {
    _Float16* lA = &As[0][w * 512];
    _Float16* lB = &Bs[0][w * 512];
    gload_lds16(gA, lA);
    gload_lds16(gA + jump, lA + 2048);
    gload_lds16(gB, lB);
    gload_lds16(gB + jump, lB + 2048);
  }
  __syncthreads();

  for (int it = 0; it < nt; ++it) {
    const int cur = it & 1;
    // issue next tile's loads early (into the other buffer)
    if (it + 1 < nt) {
      const int kt = (it + 1) * 32;
      _Float16* lA = &As[cur ^ 1][w * 512];
      _Float16* lB = &Bs[cur ^ 1][w * 512];
      gload_lds16(gA + kt, lA);
      gload_lds16(gA + jump + kt, lA + 2048);
      gload_lds16(gB + kt, lB);
      gload_lds16(gB + jump + kt, lB + 2048);
    }

    f16x8 af[4], bf[4];
    #pragma unroll
    for (int mi = 0; mi < 4; ++mi)
      af[mi] = *reinterpret_cast<const f16x8*>(&As[cur][(wr * 64 + mi * 16 + lrow) * 32 + kg * 8]);
    #pragma unroll
    for (int ni = 0; ni < 4; ++ni)
      bf[ni] = *reinterpret_cast<const f16x8*>(&Bs[cur][(wc * 64 + ni * 16 + lrow) * 32 + kg * 8]);
    #pragma unroll
    for (int mi = 0; mi < 4; ++mi) {
      #pragma unroll
      for (int ni = 0; ni < 4; ++ni)
        acc[mi][ni] = __builtin_amdgcn_mfma_f32_16x16x32_f16(af[mi], bf[ni], acc[mi][ni], 0, 0, 0);
    }
    __syncthreads();  // drains next-tile vmcnt + guards buffer reuse
  }

  OUT_T* Cz = C + (size_t)blockIdx.z * M * N;
  const int crow = (lane >> 4) * 4;
  const int ccol = lane & 15;
  #pragma unroll
  for (int mi = 0; mi < 4; ++mi) {
    #pragma unroll
    for (int ni = 0; ni < 4; ++ni) {
      #pragma unroll
      for (int r = 0; r < 4; ++r) {
        int row = m0 + wr * 64 + mi * 16 + crow + r;
        int col = n0 + wc * 64 + ni * 16 + ccol;
        Cz[(size_t)row * N + col] = (OUT_T)acc[mi][ni][r];
      }
    }
  }
}

// ---------------- sum SPLIT fp32 partials -> OUT_T ----------------
template <typename OUT_T, int SPLIT>
__global__ __launch_bounds__(256) void reduce_partials(
    const float* __restrict__ Cp, OUT_T* __restrict__ out, int n4, int stride4) {
  int idx    = blockIdx.x * 256 + threadIdx.x;
  int stride = gridDim.x * 256;
  for (int i = idx; i < n4; i += stride) {
    float4 a = reinterpret_cast<const float4*>(Cp)[i];
    #pragma unroll
    for (int s = 1; s < SPLIT; ++s) {
      float4 b = reinterpret_cast<const float4*>(Cp)[(size_t)s * stride4 + i];
      a.x += b.x; a.y += b.y; a.z += b.z; a.w += b.w;
    }
    if constexpr (sizeof(OUT_T) == 2) {
      f16x4 h = { (_Float16)a.x, (_Float16)a.y, (_Float16)a.z, (_Float16)a.w };
      reinterpret_cast<f16x4*>(out)[i] = h;
    } else {
      reinterpret_cast<float4*>(out)[i] = a;
    }
  }
}

// ---------------- in-place row softmax over N=8192 fp16 scores ----------------
__global__ __launch_bounds__(256) void softmax_rows(_Float16* __restrict__ S, int N) {
  const int t = threadIdx.x;
  f16x8* pv = reinterpret_cast<f16x8*>(S + (size_t)blockIdx.x * N);
  float v[32];
  float m = -3.0e38f;
  #pragma unroll
  for (int i = 0; i < 4; ++i) {
    f16x8 h = pv[i * 256 + t];
    #pragma unroll
    for (int e = 0; e < 8; ++e) {
      float f = (float)h[e];
      v[i * 8 + e] = f;
      m = fmaxf(m, f);
    }
  }
  #pragma unroll
  for (int o = 32; o; o >>= 1) m = fmaxf(m, __shfl_xor(m, o));
  __shared__ float redm[4];
  if ((t & 63) == 0) redm[t >> 6] = m;
  __syncthreads();
  m = fmaxf(fmaxf(redm[0], redm[1]), fmaxf(redm[2], redm[3]));

  float s = 0.f;
  #pragma unroll
  for (int i = 0; i < 32; ++i) { v[i] = __expf(v[i] - m); s += v[i]; }
  #pragma unroll
  for (int o = 32; o; o >>= 1) s += __shfl_xor(s, o);
  __shared__ float reds[4];
  if ((t & 63) == 0) reds[t >> 6] = s;
  __syncthreads();
  s = reds[0] + reds[1] + reds[2] + reds[3];
  const float inv = 1.0f / s;

  #pragma unroll
  for (int i = 0; i < 4; ++i) {
    f16x8 h;
    #pragma unroll
    for (int e = 0; e < 8; ++e) h[e] = (_Float16)(v[i * 8 + e] * inv);
    pv[i * 256 + t] = h;
  }
}

extern "C" void kernel_launch(void* const* d_in, const int* in_sizes, int n_in,
                              void* d_out, int out_size, void* d_ws, size_t ws_size,
                              hipStream_t stream) {
  const float* x        = (const float*)d_in[0];
  const float* patterns = (const float*)d_in[1];
  float* out            = (float*)d_out;
  char* ws = (char*)d_ws;

  _Float16* Xb   = (_Float16*)(ws);                          //   8 MB [4096][1024]
  _Float16* Pb   = (_Float16*)(ws + ((size_t)8  << 20));     //  16 MB [8192][1024]
  _Float16* PbT  = (_Float16*)(ws + ((size_t)24 << 20));     //  16 MB [1024][8192]
  _Float16* S    = (_Float16*)(ws + ((size_t)40 << 20));     //  64 MB [4096][8192]
  float*    part = (float*)   (ws + ((size_t)104 << 20));    //  split x 16 MB fp32 partials

  const size_t base = (size_t)104 << 20;
  const int split = (ws_size >= base + ((size_t)64 << 20)) ? 4
                  : (ws_size >= base + ((size_t)32 << 20)) ? 2 : 1;

  convert_f32_f16<<<dim3(1024), dim3(256), 0, stream>>>(x, Xb, (B_ROWS * N_NEU) / 4);
  convert_f32_f16<<<dim3(2048), dim3(256), 0, stream>>>(patterns, Pb, (N_PAT * N_NEU) / 4);
  transpose_f32_f16<<<dim3(N_NEU / 32, N_PAT / 32), dim3(32, 8), 0, stream>>>(patterns, PbT, N_PAT, N_NEU);

  const int n4 = (B_ROWS * N_NEU) / 4;
  const int stride4 = n4;

  for (int it = 0; it < 3; ++it) {
    // scores = Xb @ Pb^T  (TEMPERATURE == 1.0)  M=4096 N=8192 K=1024
    gemm_bt_db<_Float16><<<dim3(B_ROWS / 128, N_PAT / 128, 1), dim3(256), 0, stream>>>(
        Xb, Pb, S, B_ROWS, N_PAT, N_NEU, N_NEU);
    softmax_rows<<<dim3(B_ROWS), dim3(256), 0, stream>>>(S, N_PAT);

    // new_x = probs @ P == probs @ (PbT)^T   (M=4096, N=1024, K=8192)
    if (split > 1) {
      gemm_bt_db<float><<<dim3(B_ROWS / 128, N_NEU / 128, split), dim3(256), 0, stream>>>(
          S, PbT, part, B_ROWS, N_NEU, N_PAT, N_PAT / split);
      if (it < 2) {
        if (split == 4)
          reduce_partials<_Float16, 4><<<dim3(2048), dim3(256), 0, stream>>>(part, Xb, n4, stride4);
        else
          reduce_partials<_Float16, 2><<<dim3(2048), dim3(256), 0, stream>>>(part, Xb, n4, stride4);
      } else {
        if (split == 4)
          reduce_partials<float, 4><<<dim3(2048), dim3(256), 0, stream>>>(part, out, n4, stride4);
        else
          reduce_partials<float, 2><<<dim3(2048), dim3(256), 0, stream>>>(part, out, n4, stride4);
      }
    } else {
      gemm_bt_db<float><<<dim3(B_ROWS / 128, N_NEU / 128, 1), dim3(256), 0, stream>>>(
          S, PbT, part, B_ROWS, N_NEU, N_PAT, N_PAT);
      if (it < 2)
        reduce_partials<_Float16, 1><<<dim3(2048), dim3(256), 0, stream>>>(part, Xb, n4, stride4);
      else
        reduce_partials<float, 1><<<dim3(2048), dim3(256), 0, stream>>>(part, out, n4, stride4);
    }
  }
}

// Round 5
// 592.351 us; speedup vs baseline: 1.1960x; 1.0427x over previous
//
#include <hip/hip_runtime.h>
#include <hip/hip_fp16.h>
#include <stdint.h>

#define B_ROWS 4096
#define N_PAT  8192
#define N_NEU  1024

typedef _Float16 f16x8 __attribute__((ext_vector_type(8)));
typedef _Float16 f16x4 __attribute__((ext_vector_type(4)));
typedef float    f32x4 __attribute__((ext_vector_type(4)));

__device__ __forceinline__ f32x4 mfma16(f16x8 a, f16x8 b, f32x4 c) {
  return __builtin_amdgcn_mfma_f32_16x16x32_f16(a, b, c, 0, 0, 0);
}

// ---------------- fp32 -> fp16 elementwise convert (vectorized) ----------------
__global__ __launch_bounds__(256) void convert_f32_f16(
    const float* __restrict__ in, _Float16* __restrict__ out, int n4) {
  int idx    = blockIdx.x * 256 + threadIdx.x;
  int stride = gridDim.x * 256;
  for (int i = idx; i < n4; i += stride) {
    float4 v = reinterpret_cast<const float4*>(in)[i];
    f16x4 h  = { (_Float16)v.x, (_Float16)v.y, (_Float16)v.z, (_Float16)v.w };
    reinterpret_cast<f16x4*>(out)[i] = h;
  }
}

// ---------------- fp32 [rows][cols] -> fp16 transpose [cols][rows] ----------------
__global__ __launch_bounds__(256) void transpose_f32_f16(
    const float* __restrict__ in, _Float16* __restrict__ out, int rows, int cols) {
  __shared__ float tile[32][33];
  int c0 = blockIdx.x * 32, r0 = blockIdx.y * 32;
  int tx = threadIdx.x, ty = threadIdx.y;  // 32 x 8
  #pragma unroll
  for (int i = 0; i < 32; i += 8)
    tile[ty + i][tx] = in[(size_t)(r0 + ty + i) * cols + c0 + tx];
  __syncthreads();
  #pragma unroll
  for (int i = 0; i < 32; i += 8)
    out[(size_t)(c0 + ty + i) * rows + r0 + tx] = (_Float16)tile[tx][ty + i];
}

// ---------------- async global->LDS, 16B per lane, wave-uniform LDS base ----------------
__device__ __forceinline__ void gload_lds16(const _Float16* g, _Float16* l) {
  __builtin_amdgcn_global_load_lds(
      (const __attribute__((address_space(1))) uint32_t*)g,
      (__attribute__((address_space(3))) uint32_t*)l, 16, 0, 0);
}

// ================= GEMM1: 256x256 tile, 8 waves, phase-split, counted vmcnt =================
// C[M,N] = A[M,K] @ Bt[N,K]^T, f16 in, f16 out. BK=64, 2 LDS K-tile slots (128 KiB).
// Per K-tile group: 4 phases {af ds_reads -> setprio(1) 16 MFMA setprio(0) -> raw s_barrier}.
// Prefetch of tile t+2 issued AFTER the group's last read into the just-freed slot s;
// steady-state wait is s_waitcnt vmcnt(8) (tile t+1 complete, t+2 in flight) - never a
// vmcnt(0) drain (T3+T4). LDS XOR swizzle granule^(row&7), applied via pre-swizzled
// GLOBAL source (linear gload_lds dest, rule #21) + swizzled ds_read. No XCD remap.
__global__ __launch_bounds__(512, 2) void gemm1_8p(
    const _Float16* __restrict__ A, const _Float16* __restrict__ Bt,
    _Float16* __restrict__ C, int M, int N, int K) {
  __shared__ _Float16 lds[2][2][256 * 64];  // [slot][A/B][rows*64]
  const int t    = threadIdx.x;
  const int lane = t & 63;
  const int w    = t >> 6;       // wave 0..7
  const int wr   = w >> 2;       // M half (0..1)  -> wave tile 128x64
  const int wc   = w & 3;        // N quarter (0..3)
  const int m0   = blockIdx.x * 256;
  const int n0   = blockIdx.y * 256;

  // Staging: per matrix 4 issues; issue j covers rows j*64..+63 of the 256-row tile.
  // Lane covers row j*64 + w*8 + (lane>>3), LDS granule (lane&7); source granule is
  // pre-swizzled: (lane&7) ^ (row&7), row&7 == (lane>>3)&7.
  const int srow  = w * 8 + (lane >> 3);
  const int sgran = ((lane & 7) ^ ((lane >> 3) & 7)) * 8;
  const _Float16* gA = A  + (size_t)(m0 + srow) * K + sgran;
  const _Float16* gB = Bt + (size_t)(n0 + srow) * K + sgran;
  const size_t rj = (size_t)64 * K;   // row jump per issue
  const int ldst  = w * 512;          // wave-uniform LDS elem offset within an issue chunk

  const int lrow = lane & 15;
  const int kg   = lane >> 4;
  const int NT   = K >> 6;

  f32x4 acc[8][4] = {};

  // ---- prologue: tile 0 -> slot 0, tile 1 -> slot 1
  #pragma unroll
  for (int j = 0; j < 4; ++j) {
    gload_lds16(gA + j * rj,      &lds[0][0][j * 4096 + ldst]);
    gload_lds16(gB + j * rj,      &lds[0][1][j * 4096 + ldst]);
  }
  #pragma unroll
  for (int j = 0; j < 4; ++j) {
    gload_lds16(gA + j * rj + 64, &lds[1][0][j * 4096 + ldst]);
    gload_lds16(gB + j * rj + 64, &lds[1][1][j * 4096 + ldst]);
  }
  asm volatile("s_waitcnt vmcnt(8)" ::: "memory");  // tile 0 landed; tile 1 in flight
  __builtin_amdgcn_s_barrier();
  __builtin_amdgcn_sched_barrier(0);

  for (int tt = 0; tt < NT; ++tt) {
    const int s = tt & 1;
    const _Float16* As = lds[s][0];
    const _Float16* Bs = lds[s][1];

    // B fragments for the whole K-tile (32 VGPR, held across phases)
    f16x8 bf[4][2];
    #pragma unroll
    for (int ni = 0; ni < 4; ++ni) {
      const int br = wc * 64 + ni * 16 + lrow;
      #pragma unroll
      for (int ks = 0; ks < 2; ++ks)
        bf[ni][ks] = *reinterpret_cast<const f16x8*>(
            &Bs[br * 64 + (((ks * 4 + kg) ^ (br & 7)) * 8)]);
    }

    #pragma unroll
    for (int p = 0; p < 4; ++p) {
      f16x8 af[2][2];
      #pragma unroll
      for (int j = 0; j < 2; ++j) {
        const int ar = wr * 128 + (p * 2 + j) * 16 + lrow;
        #pragma unroll
        for (int ks = 0; ks < 2; ++ks)
          af[j][ks] = *reinterpret_cast<const f16x8*>(
              &As[ar * 64 + (((ks * 4 + kg) ^ (ar & 7)) * 8)]);
      }
      __builtin_amdgcn_s_setprio(1);
      #pragma unroll
      for (int j = 0; j < 2; ++j) {
        #pragma unroll
        for (int ni = 0; ni < 4; ++ni) {
          acc[p * 2 + j][ni] = mfma16(af[j][0], bf[ni][0], acc[p * 2 + j][ni]);
          acc[p * 2 + j][ni] = mfma16(af[j][1], bf[ni][1], acc[p * 2 + j][ni]);
        }
      }
      __builtin_amdgcn_s_setprio(0);
      if (p < 3) __builtin_amdgcn_s_barrier();  // raw: no vmcnt drain
    }

    // all waves finished reading slot s (their MFMAs consumed every read)
    __builtin_amdgcn_s_barrier();
    __builtin_amdgcn_sched_barrier(0);
    if (tt + 2 < NT) {
      const int kt = (tt + 2) * 64;
      #pragma unroll
      for (int j = 0; j < 4; ++j) {
        gload_lds16(gA + j * rj + kt, &lds[s][0][j * 4096 + ldst]);
        gload_lds16(gB + j * rj + kt, &lds[s][1][j * 4096 + ldst]);
      }
      asm volatile("s_waitcnt vmcnt(8)" ::: "memory");  // t+1 complete, t+2 in flight
    } else {
      asm volatile("s_waitcnt vmcnt(0)" ::: "memory");  // epilogue of pipeline
    }
    __builtin_amdgcn_s_barrier();
    __builtin_amdgcn_sched_barrier(0);
  }

  // C/D layout: col = lane&15, row = (lane>>4)*4 + reg
  const int crow = (lane >> 4) * 4;
  const int ccol = lane & 15;
  #pragma unroll
  for (int mi = 0; mi < 8; ++mi) {
    #pragma unroll
    for (int ni = 0; ni < 4; ++ni) {
      #pragma unroll
      for (int r = 0; r < 4; ++r) {
        int row = m0 + wr * 128 + mi * 16 + crow + r;
        int col = n0 + wc * 64 + ni * 16 + ccol;
        C[(size_t)row * N + col] = (_Float16)acc[mi][ni][r];
      }
    }
  }
}

// ---------------- C[z][M,N] = A[M,k0:k1] @ Bt[N,k0:k1]^T, dbuf + issue-early ----------------
// (unchanged round-4 structure; used for GEMM2)
template <typename OUT_T>
__global__ __launch_bounds__(256, 4) void gemm_bt_db(
    const _Float16* __restrict__ A, const _Float16* __restrict__ Bt,
    OUT_T* __restrict__ C, int M, int N, int K, int KS) {
  __shared__ _Float16 As[2][128 * 32];
  __shared__ _Float16 Bs[2][128 * 32];
  const int t    = threadIdx.x;
  const int lane = t & 63;
  const int w    = t >> 6;
  const int wr   = w >> 1;
  const int wc   = w & 1;
  const int m0   = blockIdx.x * 128;
  const int n0   = blockIdx.y * 128;
  const int k0   = blockIdx.z * KS;

  const int srow = w * 16 + (lane >> 2);
  const int scol = (lane & 3) * 8;
  const _Float16* gA = A  + (size_t)(m0 + srow) * K + scol + k0;
  const _Float16* gB = Bt + (size_t)(n0 + srow) * K + scol + k0;
  const size_t jump = (size_t)64 * K;

  const int lrow = lane & 15;
  const int kg   = lane >> 4;
  const int nt   = KS / 32;

  f32x4 acc[4][4] = {};

  {
    _Float16* lA = &As[0][w * 512];
    _Float16* lB = &Bs[0][w * 512];
    gload_lds16(gA, lA);
    gload_lds16(gA + jump, lA + 2048);
    gload_lds16(gB, lB);
    gload_lds16(gB + jump, lB + 2048);
  }
  __syncthreads();

  for (int it = 0; it < nt; ++it) {
    const int cur = it & 1;
    if (it + 1 < nt) {
      const int kt = (it + 1) * 32;
      _Float16* lA = &As[cur ^ 1][w * 512];
      _Float16* lB = &Bs[cur ^ 1][w * 512];
      gload_lds16(gA + kt, lA);
      gload_lds16(gA + jump + kt, lA + 2048);
      gload_lds16(gB + kt, lB);
      gload_lds16(gB + jump + kt, lB + 2048);
    }

    f16x8 af[4], bf[4];
    #pragma unroll
    for (int mi = 0; mi < 4; ++mi)
      af[mi] = *reinterpret_cast<const f16x8*>(&As[cur][(wr * 64 + mi * 16 + lrow) * 32 + kg * 8]);
    #pragma unroll
    for (int ni = 0; ni < 4; ++ni)
      bf[ni] = *reinterpret_cast<const f16x8*>(&Bs[cur][(wc * 64 + ni * 16 + lrow) * 32 + kg * 8]);
    #pragma unroll
    for (int mi = 0; mi < 4; ++mi) {
      #pragma unroll
      for (int ni = 0; ni < 4; ++ni)
        acc[mi][ni] = __builtin_amdgcn_mfma_f32_16x16x32_f16(af[mi], bf[ni], acc[mi][ni], 0, 0, 0);
    }
    __syncthreads();
  }

  OUT_T* Cz = C + (size_t)blockIdx.z * M * N;
  const int crow = (lane >> 4) * 4;
  const int ccol = lane & 15;
  #pragma unroll
  for (int mi = 0; mi < 4; ++mi) {
    #pragma unroll
    for (int ni = 0; ni < 4; ++ni) {
      #pragma unroll
      for (int r = 0; r < 4; ++r) {
        int row = m0 + wr * 64 + mi * 16 + crow + r;
        int col = n0 + wc * 64 + ni * 16 + ccol;
        Cz[(size_t)row * N + col] = (OUT_T)acc[mi][ni][r];
      }
    }
  }
}

// ---------------- sum SPLIT fp32 partials -> OUT_T ----------------
template <typename OUT_T, int SPLIT>
__global__ __launch_bounds__(256) void reduce_partials(
    const float* __restrict__ Cp, OUT_T* __restrict__ out, int n4, int stride4) {
  int idx    = blockIdx.x * 256 + threadIdx.x;
  int stride = gridDim.x * 256;
  for (int i = idx; i < n4; i += stride) {
    float4 a = reinterpret_cast<const float4*>(Cp)[i];
    #pragma unroll
    for (int s = 1; s < SPLIT; ++s) {
      float4 b = reinterpret_cast<const float4*>(Cp)[(size_t)s * stride4 + i];
      a.x += b.x; a.y += b.y; a.z += b.z; a.w += b.w;
    }
    if constexpr (sizeof(OUT_T) == 2) {
      f16x4 h = { (_Float16)a.x, (_Float16)a.y, (_Float16)a.z, (_Float16)a.w };
      reinterpret_cast<f16x4*>(out)[i] = h;
    } else {
      reinterpret_cast<float4*>(out)[i] = a;
    }
  }
}

// ---------------- in-place row softmax over N=8192 fp16 scores ----------------
__global__ __launch_bounds__(256) void softmax_rows(_Float16* __restrict__ S, int N) {
  const int t = threadIdx.x;
  f16x8* pv = reinterpret_cast<f16x8*>(S + (size_t)blockIdx.x * N);
  float v[32];
  float m = -3.0e38f;
  #pragma unroll
  for (int i = 0; i < 4; ++i) {
    f16x8 h = pv[i * 256 + t];
    #pragma unroll
    for (int e = 0; e < 8; ++e) {
      float f = (float)h[e];
      v[i * 8 + e] = f;
      m = fmaxf(m, f);
    }
  }
  #pragma unroll
  for (int o = 32; o; o >>= 1) m = fmaxf(m, __shfl_xor(m, o));
  __shared__ float redm[4];
  if ((t & 63) == 0) redm[t >> 6] = m;
  __syncthreads();
  m = fmaxf(fmaxf(redm[0], redm[1]), fmaxf(redm[2], redm[3]));

  float s = 0.f;
  #pragma unroll
  for (int i = 0; i < 32; ++i) { v[i] = __expf(v[i] - m); s += v[i]; }
  #pragma unroll
  for (int o = 32; o; o >>= 1) s += __shfl_xor(s, o);
  __shared__ float reds[4];
  if ((t & 63) == 0) reds[t >> 6] = s;
  __syncthreads();
  s = reds[0] + reds[1] + reds[2] + reds[3];
  const float inv = 1.0f / s;

  #pragma unroll
  for (int i = 0; i < 4; ++i) {
    f16x8 h;
    #pragma unroll
    for (int e = 0; e < 8; ++e) h[e] = (_Float16)(v[i * 8 + e] * inv);
    pv[i * 256 + t] = h;
  }
}

extern "C" void kernel_launch(void* const* d_in, const int* in_sizes, int n_in,
                              void* d_out, int out_size, void* d_ws, size_t ws_size,
                              hipStream_t stream) {
  const float* x        = (const float*)d_in[0];
  const float* patterns = (const float*)d_in[1];
  float* out            = (float*)d_out;
  char* ws = (char*)d_ws;

  _Float16* Xb   = (_Float16*)(ws);                          //   8 MB [4096][1024]
  _Float16* Pb   = (_Float16*)(ws + ((size_t)8  << 20));     //  16 MB [8192][1024]
  _Float16* PbT  = (_Float16*)(ws + ((size_t)24 << 20));     //  16 MB [1024][8192]
  _Float16* S    = (_Float16*)(ws + ((size_t)40 << 20));     //  64 MB [4096][8192]
  float*    part = (float*)   (ws + ((size_t)104 << 20));    //  split x 16 MB fp32 partials

  const size_t base = (size_t)104 << 20;
  const int split = (ws_size >= base + ((size_t)64 << 20)) ? 4
                  : (ws_size >= base + ((size_t)32 << 20)) ? 2 : 1;

  convert_f32_f16<<<dim3(1024), dim3(256), 0, stream>>>(x, Xb, (B_ROWS * N_NEU) / 4);
  convert_f32_f16<<<dim3(2048), dim3(256), 0, stream>>>(patterns, Pb, (N_PAT * N_NEU) / 4);
  transpose_f32_f16<<<dim3(N_NEU / 32, N_PAT / 32), dim3(32, 8), 0, stream>>>(patterns, PbT, N_PAT, N_NEU);

  const int n4 = (B_ROWS * N_NEU) / 4;
  const int stride4 = n4;

  for (int it = 0; it < 3; ++it) {
    // scores = Xb @ Pb^T  (TEMPERATURE == 1.0)  M=4096 N=8192 K=1024
    gemm1_8p<<<dim3(B_ROWS / 256, N_PAT / 256), dim3(512), 0, stream>>>(
        Xb, Pb, S, B_ROWS, N_PAT, N_NEU);
    softmax_rows<<<dim3(B_ROWS), dim3(256), 0, stream>>>(S, N_PAT);

    // new_x = probs @ P == probs @ (PbT)^T   (M=4096, N=1024, K=8192)
    if (split > 1) {
      gemm_bt_db<float><<<dim3(B_ROWS / 128, N_NEU / 128, split), dim3(256), 0, stream>>>(
          S, PbT, part, B_ROWS, N_NEU, N_PAT, N_PAT / split);
      if (it < 2) {
        if (split == 4)
          reduce_partials<_Float16, 4><<<dim3(2048), dim3(256), 0, stream>>>(part, Xb, n4, stride4);
        else
          reduce_partials<_Float16, 2><<<dim3(2048), dim3(256), 0, stream>>>(part, Xb, n4, stride4);
      } else {
        if (split == 4)
          reduce_partials<float, 4><<<dim3(2048), dim3(256), 0, stream>>>(part, out, n4, stride4);
        else
          reduce_partials<float, 2><<<dim3(2048), dim3(256), 0, stream>>>(part, out, n4, stride4);
      }
    } else {
      gemm_bt_db<float><<<dim3(B_ROWS / 128, N_NEU / 128, 1), dim3(256), 0, stream>>>(
          S, PbT, part, B_ROWS, N_NEU, N_PAT, N_PAT);
      if (it < 2)
        reduce_partials<_Float16, 1><<<dim3(2048), dim3(256), 0, stream>>>(part, Xb, n4, stride4);
      else
        reduce_partials<float, 1><<<dim3(2048), dim3(256), 0, stream>>>(part, out, n4, stride4);
    }
  }
}